// Round 1
// baseline (215.437 us; speedup 1.0000x reference)
//
#include <hip/hip_runtime.h>

// Embedding gather: out[r, :] = table[ids[r], :]
//   ids:   [819200] int32 (BATCH*HIST flattened), values in [0, 1e6)
//   table: [1e6, 32] fp32  -> treated as [1e6 * 8] float4 (row = 8 float4)
//   out:   [819200, 32] fp32 -> [819200 * 8] float4
//
// One thread per float4: 8 consecutive lanes cover one 128B row, so both
// the gathered read and the write are coalesced 128B segments. ids[row]
// is a same-address broadcast across those 8 lanes (L1-served).
__global__ void embed_gather_kernel(const int* __restrict__ ids,
                                    const float4* __restrict__ table,
                                    float4* __restrict__ out,
                                    int n_vec) {
    int i = blockIdx.x * blockDim.x + threadIdx.x;
    if (i >= n_vec) return;
    int row = i >> 3;        // which id
    int sub = i & 7;         // which float4 within the 32-float row
    long id = (long)ids[row];
    out[i] = table[id * 8 + sub];
}

extern "C" void kernel_launch(void* const* d_in, const int* in_sizes, int n_in,
                              void* d_out, int out_size, void* d_ws, size_t ws_size,
                              hipStream_t stream) {
    const int* ids      = (const int*)d_in[0];      // [BATCH*HIST]
    const float4* table = (const float4*)d_in[1];   // [VOCAB*8]
    float4* out         = (float4*)d_out;           // [BATCH*HIST*8]

    int n_rows = in_sizes[0];        // 819200
    int n_vec  = n_rows * 8;         // one float4 per thread

    const int block = 256;
    int grid = (n_vec + block - 1) / block;
    embed_gather_kernel<<<grid, block, 0, stream>>>(ids, table, out, n_vec);
}